// Round 6
// baseline (284.018 us; speedup 1.0000x reference)
//
#include <hip/hip_runtime.h>
#include <hip/hip_bf16.h>

#define VOCAB 50257
#define FEAT 512
#define NTOK (32 * 4096)
#define EPS 1e-12f
#define NFT 8              // number of 64-row feature tiles
#define NREP 3             // diagnostic work multiplier in K2

typedef float f32x4 __attribute__((ext_vector_type(4)));

__device__ __forceinline__ unsigned short f2bf(float x) {
    __hip_bfloat16 h = __float2bfloat16(x);  // RNE
    unsigned short u; __builtin_memcpy(&u, &h, 2); return u;
}
__device__ __forceinline__ float bfround(float x) {
    return __bfloat162float(__float2bfloat16(x));
}
__device__ __forceinline__ float bflo(unsigned int w) {
    unsigned int u = w << 16; float f; __builtin_memcpy(&f, &u, 4); return f;
}
__device__ __forceinline__ float bfhi(unsigned int w) {
    unsigned int u = w & 0xffff0000u; float f; __builtin_memcpy(&f, &u, 4); return f;
}

// ---------------------------------------------------------------------------
// K1 (unchanged from R3 best): Wt[v][f] = bf16(W[f][v] + b[f]) + per-tile
// partial sum-of-squares partial[ftile][v].
// ---------------------------------------------------------------------------
__global__ __launch_bounds__(256) void transpose_bias_bf16(
        const float* __restrict__ W, const float* __restrict__ b,
        unsigned short* __restrict__ Wt, float* __restrict__ partial) {
    __shared__ float tile[64][65];
    __shared__ float psum[4][64];
    const int t = threadIdx.x, l = t & 63, w = t >> 6;
    const int v0 = blockIdx.x * 64, f0 = blockIdx.y * 64;
    const int c = l & 15, r = l >> 4;
    const int vb = v0 + c * 4;

    float p[4] = {0.f, 0.f, 0.f, 0.f};
#pragma unroll
    for (int k = 0; k < 4; ++k) {
        const int fl = w * 16 + k * 4 + r;
        const int f  = f0 + fl;
        f32x4 x;
        if (vb + 3 < VOCAB) {
            __builtin_memcpy(&x, W + (size_t)f * VOCAB + vb, 16);
        } else {
#pragma unroll
            for (int q = 0; q < 4; ++q)
                x[q] = (vb + q < VOCAB) ? W[(size_t)f * VOCAB + vb + q] : 0.0f;
        }
        const float bf = b[f];
#pragma unroll
        for (int q = 0; q < 4; ++q) {
            const float xi = x[q] + bf;
            tile[fl][c * 4 + q] = xi;
            const float xr = bfround(xi);
            p[q] += xr * xr;
        }
    }
#pragma unroll
    for (int q = 0; q < 4; ++q) {
        float s = p[q];
        s += __shfl_xor(s, 16, 64);
        s += __shfl_xor(s, 32, 64);
        if (r == 0) psum[w][c * 4 + q] = s;
    }
    __syncthreads();
    if (t < 64) {
        const int v = v0 + t;
        if (v < VOCAB)
            partial[blockIdx.y * VOCAB + v] =
                psum[0][t] + psum[1][t] + psum[2][t] + psum[3][t];
    }
#pragma unroll
    for (int ps = 0; ps < 2; ++ps) {
        const int idx = t + 256 * ps;
        const int vl = idx >> 3, ch = idx & 7;
        const int v = v0 + vl;
        if (v < VOCAB) {
            unsigned int pk[4];
#pragma unroll
            for (int j = 0; j < 4; ++j) {
                const int f = ch * 8 + 2 * j;
                pk[j] = (unsigned int)f2bf(tile[f][vl]) |
                        ((unsigned int)f2bf(tile[f + 1][vl]) << 16);
            }
            *(uint4*)(Wt + (size_t)v * FEAT + f0 + ch * 8) =
                make_uint4(pk[0], pk[1], pk[2], pk[3]);
        }
    }
}

// ---------------------------------------------------------------------------
// K2 DIAGNOSTIC (x3 work, one dispatch -> cracks rocprof top-5):
// each wave handles 3 distinct tokens; every token is written exactly 3 times
// with identical values (deterministic). Inner math identical to R3's K2.
// ---------------------------------------------------------------------------
__global__ __launch_bounds__(256) void encode_bf16_x3(
        const int* __restrict__ ids, const unsigned short* __restrict__ Wt,
        const float* __restrict__ partial, float* __restrict__ out) {
    const int wv   = (int)((blockIdx.x * (unsigned long long)blockDim.x + threadIdx.x) >> 6);
    const int lane = threadIdx.x & 63;
    if (wv >= NTOK) return;

    const int offs[NREP] = {0, 40009, 90001};

#pragma unroll 1
    for (int rp = 0; rp < NREP; ++rp) {
        int tok = wv + offs[rp];
        if (tok >= NTOK) tok -= NTOK;

        const int id = ids[tok];
        const uint4 rr = *((const uint4*)(Wt + (size_t)id * FEAT) + lane);

        float s = 0.0f;
#pragma unroll
        for (int j = 0; j < NFT; ++j) s += partial[j * VOCAB + id];
        const float inv = 1.0f / fmaxf(sqrtf(s), EPS);

        float x[8];
        x[0] = bflo(rr.x); x[1] = bfhi(rr.x);
        x[2] = bflo(rr.y); x[3] = bfhi(rr.y);
        x[4] = bflo(rr.z); x[5] = bfhi(rr.z);
        x[6] = bflo(rr.w); x[7] = bfhi(rr.w);

        f32x4 o0 = {x[0] * inv, x[1] * inv, x[2] * inv, x[3] * inv};
        f32x4 o1 = {x[4] * inv, x[5] * inv, x[6] * inv, x[7] * inv};
        f32x4* dst = (f32x4*)(out + (size_t)tok * FEAT + lane * 8);
        __builtin_nontemporal_store(o0, dst);
        __builtin_nontemporal_store(o1, dst + 1);
    }
}

// ---------------------------------------------------------------------------
// Fallback (ws too small): direct strided gather from W with full reduction.
// ---------------------------------------------------------------------------
__global__ __launch_bounds__(256) void encode_direct(const int* __restrict__ ids,
                                                     const float* __restrict__ W,
                                                     const float* __restrict__ bias,
                                                     float* __restrict__ out) {
    const int tok  = (int)((blockIdx.x * (unsigned long long)blockDim.x + threadIdx.x) >> 6);
    const int lane = threadIdx.x & 63;
    if (tok >= NTOK) return;
    const int id = ids[tok];
    float x[8];
    float s = 0.0f;
#pragma unroll
    for (int j = 0; j < 8; ++j) {
        const int f = lane * 8 + j;
        x[j] = W[(size_t)f * VOCAB + id] + bias[f];
        s += x[j] * x[j];
    }
#pragma unroll
    for (int off = 32; off > 0; off >>= 1)
        s += __shfl_xor(s, off, 64);
    const float inv = 1.0f / fmaxf(sqrtf(s), EPS);
    float4 o0 = make_float4(x[0] * inv, x[1] * inv, x[2] * inv, x[3] * inv);
    float4 o1 = make_float4(x[4] * inv, x[5] * inv, x[6] * inv, x[7] * inv);
    float4* dst = (float4*)(out + (size_t)tok * FEAT + lane * 8);
    dst[0] = o0;
    dst[1] = o1;
}

extern "C" void kernel_launch(void* const* d_in, const int* in_sizes, int n_in,
                              void* d_out, int out_size, void* d_ws, size_t ws_size,
                              hipStream_t stream) {
    const int*   ids  = (const int*)d_in[0];
    const float* W    = (const float*)d_in[1];
    const float* bias = (const float*)d_in[2];
    float*       out  = (float*)d_out;

    const size_t wt_bytes   = (size_t)VOCAB * FEAT * sizeof(unsigned short); // 51.46 MB
    const size_t part_bytes = (size_t)NFT * VOCAB * sizeof(float);           // 1.6 MB
    const int nblocks = NTOK / 4;

    if (ws_size >= wt_bytes + part_bytes) {
        unsigned short* Wt = (unsigned short*)d_ws;
        float* partial     = (float*)((char*)d_ws + wt_bytes);
        dim3 tgrid((VOCAB + 63) / 64, FEAT / 64);       // (786, 8)
        transpose_bias_bf16<<<tgrid, 256, 0, stream>>>(W, bias, Wt, partial);
        encode_bf16_x3<<<nblocks, 256, 0, stream>>>(ids, Wt, partial, out);
    } else {
        encode_direct<<<nblocks, 256, 0, stream>>>(ids, W, bias, out);
    }
}

// Round 7
// 133.302 us; speedup vs baseline: 2.1306x; 2.1306x over previous
//
#include <hip/hip_runtime.h>
#include <hip/hip_bf16.h>

#define VOCAB 50257
#define FEAT 512
#define NTOK (32 * 4096)
#define EPS 1e-12f
#define NFT 8              // number of 64-row feature tiles

typedef float f32x4 __attribute__((ext_vector_type(4)));

__device__ __forceinline__ unsigned short f2bf(float x) {
    __hip_bfloat16 h = __float2bfloat16(x);  // RNE
    unsigned short u; __builtin_memcpy(&u, &h, 2); return u;
}
__device__ __forceinline__ float bfround(float x) {
    return __bfloat162float(__float2bfloat16(x));
}
__device__ __forceinline__ float bflo(unsigned int w) {
    unsigned int u = w << 16; float f; __builtin_memcpy(&f, &u, 4); return f;
}
__device__ __forceinline__ float bfhi(unsigned int w) {
    unsigned int u = w & 0xffff0000u; float f; __builtin_memcpy(&f, &u, 4); return f;
}

// ---------------------------------------------------------------------------
// K1 (unchanged, proven): Wt[v][f] = bf16(W[f][v] + b[f]) + per-tile partial
// sum-of-squares partial[ftile][v] of the bf16-rounded values.
// ---------------------------------------------------------------------------
__global__ __launch_bounds__(256) void transpose_bias_bf16(
        const float* __restrict__ W, const float* __restrict__ b,
        unsigned short* __restrict__ Wt, float* __restrict__ partial) {
    __shared__ float tile[64][65];
    __shared__ float psum[4][64];
    const int t = threadIdx.x, l = t & 63, w = t >> 6;
    const int v0 = blockIdx.x * 64, f0 = blockIdx.y * 64;
    const int c = l & 15, r = l >> 4;
    const int vb = v0 + c * 4;

    float p[4] = {0.f, 0.f, 0.f, 0.f};
#pragma unroll
    for (int k = 0; k < 4; ++k) {
        const int fl = w * 16 + k * 4 + r;
        const int f  = f0 + fl;
        f32x4 x;
        if (vb + 3 < VOCAB) {
            __builtin_memcpy(&x, W + (size_t)f * VOCAB + vb, 16);
        } else {
#pragma unroll
            for (int q = 0; q < 4; ++q)
                x[q] = (vb + q < VOCAB) ? W[(size_t)f * VOCAB + vb + q] : 0.0f;
        }
        const float bf = b[f];
#pragma unroll
        for (int q = 0; q < 4; ++q) {
            const float xi = x[q] + bf;
            tile[fl][c * 4 + q] = xi;
            const float xr = bfround(xi);
            p[q] += xr * xr;
        }
    }
#pragma unroll
    for (int q = 0; q < 4; ++q) {
        float s = p[q];
        s += __shfl_xor(s, 16, 64);
        s += __shfl_xor(s, 32, 64);
        if (r == 0) psum[w][c * 4 + q] = s;
    }
    __syncthreads();
    if (t < 64) {
        const int v = v0 + t;
        if (v < VOCAB)
            partial[blockIdx.y * VOCAB + v] =
                psum[0][t] + psum[1][t] + psum[2][t] + psum[3][t];
    }
#pragma unroll
    for (int ps = 0; ps < 2; ++ps) {
        const int idx = t + 256 * ps;
        const int vl = idx >> 3, ch = idx & 7;
        const int v = v0 + vl;
        if (v < VOCAB) {
            unsigned int pk[4];
#pragma unroll
            for (int j = 0; j < 4; ++j) {
                const int f = ch * 8 + 2 * j;
                pk[j] = (unsigned int)f2bf(tile[f][vl]) |
                        ((unsigned int)f2bf(tile[f + 1][vl]) << 16);
            }
            *(uint4*)(Wt + (size_t)v * FEAT + f0 + ch * 8) =
                make_uint4(pk[0], pk[1], pk[2], pk[3]);
        }
    }
}

// ---------------------------------------------------------------------------
// K1.5: inv[v] = 1/max(sqrt(sum_j partial[j][v]), eps). 0.2 MB, L2-resident.
// ---------------------------------------------------------------------------
__global__ __launch_bounds__(256) void norm_table(const float* __restrict__ partial,
                                                  float* __restrict__ invn) {
    const int v = blockIdx.x * 256 + threadIdx.x;
    if (v >= VOCAB) return;
    float s = 0.0f;
#pragma unroll
    for (int j = 0; j < NFT; ++j) s += partial[j * VOCAB + v];
    invn[v] = 1.0f / fmaxf(sqrtf(s), EPS);
}

// ---------------------------------------------------------------------------
// K2 (ILP-2): each wave handles 2 adjacent tokens -> two independent
// id->gather chains in flight, 4KB contiguous NT stores, half the waves.
// ---------------------------------------------------------------------------
__global__ __launch_bounds__(256) void encode_bf16_ilp2(
        const int* __restrict__ ids, const unsigned short* __restrict__ Wt,
        const float* __restrict__ invn, float* __restrict__ out) {
    const int wv   = (int)((blockIdx.x * (unsigned long long)blockDim.x + threadIdx.x) >> 6);
    const int lane = threadIdx.x & 63;
    const int tok0 = wv * 2;
    if (tok0 >= NTOK) return;

    const int id0 = ids[tok0];
    const int id1 = ids[tok0 + 1];

    const uint4 r0 = *((const uint4*)(Wt + (size_t)id0 * FEAT) + lane);
    const uint4 r1 = *((const uint4*)(Wt + (size_t)id1 * FEAT) + lane);
    const float i0 = invn[id0];
    const float i1 = invn[id1];

    f32x4 a0 = {bflo(r0.x) * i0, bfhi(r0.x) * i0, bflo(r0.y) * i0, bfhi(r0.y) * i0};
    f32x4 a1 = {bflo(r0.z) * i0, bfhi(r0.z) * i0, bflo(r0.w) * i0, bfhi(r0.w) * i0};
    f32x4 c0 = {bflo(r1.x) * i1, bfhi(r1.x) * i1, bflo(r1.y) * i1, bfhi(r1.y) * i1};
    f32x4 c1 = {bflo(r1.z) * i1, bfhi(r1.z) * i1, bflo(r1.w) * i1, bfhi(r1.w) * i1};

    f32x4* d0 = (f32x4*)(out + (size_t)tok0 * FEAT + lane * 8);
    f32x4* d1 = (f32x4*)(out + (size_t)(tok0 + 1) * FEAT + lane * 8);
    __builtin_nontemporal_store(a0, d0);
    __builtin_nontemporal_store(a1, d0 + 1);
    __builtin_nontemporal_store(c0, d1);
    __builtin_nontemporal_store(c1, d1 + 1);
}

// ---------------------------------------------------------------------------
// Fallback (ws too small): direct strided gather from W with full reduction.
// ---------------------------------------------------------------------------
__global__ __launch_bounds__(256) void encode_direct(const int* __restrict__ ids,
                                                     const float* __restrict__ W,
                                                     const float* __restrict__ bias,
                                                     float* __restrict__ out) {
    const int tok  = (int)((blockIdx.x * (unsigned long long)blockDim.x + threadIdx.x) >> 6);
    const int lane = threadIdx.x & 63;
    if (tok >= NTOK) return;
    const int id = ids[tok];
    float x[8];
    float s = 0.0f;
#pragma unroll
    for (int j = 0; j < 8; ++j) {
        const int f = lane * 8 + j;
        x[j] = W[(size_t)f * VOCAB + id] + bias[f];
        s += x[j] * x[j];
    }
#pragma unroll
    for (int off = 32; off > 0; off >>= 1)
        s += __shfl_xor(s, off, 64);
    const float inv = 1.0f / fmaxf(sqrtf(s), EPS);
    float4 o0 = make_float4(x[0] * inv, x[1] * inv, x[2] * inv, x[3] * inv);
    float4 o1 = make_float4(x[4] * inv, x[5] * inv, x[6] * inv, x[7] * inv);
    float4* dst = (float4*)(out + (size_t)tok * FEAT + lane * 8);
    dst[0] = o0;
    dst[1] = o1;
}

extern "C" void kernel_launch(void* const* d_in, const int* in_sizes, int n_in,
                              void* d_out, int out_size, void* d_ws, size_t ws_size,
                              hipStream_t stream) {
    const int*   ids  = (const int*)d_in[0];
    const float* W    = (const float*)d_in[1];
    const float* bias = (const float*)d_in[2];
    float*       out  = (float*)d_out;

    const size_t wt_bytes   = (size_t)VOCAB * FEAT * sizeof(unsigned short); // 51.46 MB
    const size_t part_bytes = (size_t)NFT * VOCAB * sizeof(float);           // 1.6 MB
    const size_t inv_bytes  = (size_t)VOCAB * sizeof(float);                 // 0.2 MB

    if (ws_size >= wt_bytes + part_bytes + inv_bytes) {
        unsigned short* Wt = (unsigned short*)d_ws;
        float* partial     = (float*)((char*)d_ws + wt_bytes);
        float* invn        = (float*)((char*)d_ws + wt_bytes + part_bytes);
        dim3 tgrid((VOCAB + 63) / 64, FEAT / 64);       // (786, 8)
        transpose_bias_bf16<<<tgrid, 256, 0, stream>>>(W, bias, Wt, partial);
        norm_table<<<(VOCAB + 255) / 256, 256, 0, stream>>>(partial, invn);
        // NTOK/2 waves, 4 waves per 256-thr block
        encode_bf16_ilp2<<<NTOK / 8, 256, 0, stream>>>(ids, Wt, invn, out);
    } else {
        encode_direct<<<NTOK / 4, 256, 0, stream>>>(ids, W, bias, out);
    }
}

// Round 8
// 109.197 us; speedup vs baseline: 2.6010x; 1.2207x over previous
//
#include <hip/hip_runtime.h>
#include <hip/hip_bf16.h>

#define VOCAB 50257
#define FEAT 512
#define NTOK (32 * 4096)
#define EPS 1e-12f
#define NFT 8              // number of 64-row feature tiles

typedef float f32x4 __attribute__((ext_vector_type(4)));

__device__ __forceinline__ unsigned short f2bf(float x) {
    __hip_bfloat16 h = __float2bfloat16(x);  // RNE
    unsigned short u; __builtin_memcpy(&u, &h, 2); return u;
}
__device__ __forceinline__ float bfround(float x) {
    return __bfloat162float(__float2bfloat16(x));
}
__device__ __forceinline__ float bflo(unsigned int w) {
    unsigned int u = w << 16; float f; __builtin_memcpy(&f, &u, 4); return f;
}
__device__ __forceinline__ float bfhi(unsigned int w) {
    unsigned int u = w & 0xffff0000u; float f; __builtin_memcpy(&f, &u, 4); return f;
}

// ---------------------------------------------------------------------------
// K1 (unchanged, proven): Wt[v][f] = bf16(W[f][v] + b[f]) + per-tile partial
// sum-of-squares partial[ftile][v] of the bf16-rounded values.
// ---------------------------------------------------------------------------
__global__ __launch_bounds__(256) void transpose_bias_bf16(
        const float* __restrict__ W, const float* __restrict__ b,
        unsigned short* __restrict__ Wt, float* __restrict__ partial) {
    __shared__ float tile[64][65];
    __shared__ float psum[4][64];
    const int t = threadIdx.x, l = t & 63, w = t >> 6;
    const int v0 = blockIdx.x * 64, f0 = blockIdx.y * 64;
    const int c = l & 15, r = l >> 4;
    const int vb = v0 + c * 4;

    float p[4] = {0.f, 0.f, 0.f, 0.f};
#pragma unroll
    for (int k = 0; k < 4; ++k) {
        const int fl = w * 16 + k * 4 + r;
        const int f  = f0 + fl;
        f32x4 x;
        if (vb + 3 < VOCAB) {
            __builtin_memcpy(&x, W + (size_t)f * VOCAB + vb, 16);
        } else {
#pragma unroll
            for (int q = 0; q < 4; ++q)
                x[q] = (vb + q < VOCAB) ? W[(size_t)f * VOCAB + vb + q] : 0.0f;
        }
        const float bf = b[f];
#pragma unroll
        for (int q = 0; q < 4; ++q) {
            const float xi = x[q] + bf;
            tile[fl][c * 4 + q] = xi;
            const float xr = bfround(xi);
            p[q] += xr * xr;
        }
    }
#pragma unroll
    for (int q = 0; q < 4; ++q) {
        float s = p[q];
        s += __shfl_xor(s, 16, 64);
        s += __shfl_xor(s, 32, 64);
        if (r == 0) psum[w][c * 4 + q] = s;
    }
    __syncthreads();
    if (t < 64) {
        const int v = v0 + t;
        if (v < VOCAB)
            partial[blockIdx.y * VOCAB + v] =
                psum[0][t] + psum[1][t] + psum[2][t] + psum[3][t];
    }
#pragma unroll
    for (int ps = 0; ps < 2; ++ps) {
        const int idx = t + 256 * ps;
        const int vl = idx >> 3, ch = idx & 7;
        const int v = v0 + vl;
        if (v < VOCAB) {
            unsigned int pk[4];
#pragma unroll
            for (int j = 0; j < 4; ++j) {
                const int f = ch * 8 + 2 * j;
                pk[j] = (unsigned int)f2bf(tile[f][vl]) |
                        ((unsigned int)f2bf(tile[f + 1][vl]) << 16);
            }
            *(uint4*)(Wt + (size_t)v * FEAT + f0 + ch * 8) =
                make_uint4(pk[0], pk[1], pk[2], pk[3]);
        }
    }
}

// ---------------------------------------------------------------------------
// K1.5: inv[v] = 1/max(sqrt(sum_j partial[j][v]), eps). 0.2 MB, L2-resident.
// ---------------------------------------------------------------------------
__global__ __launch_bounds__(256) void norm_table(const float* __restrict__ partial,
                                                  float* __restrict__ invn) {
    const int v = blockIdx.x * 256 + threadIdx.x;
    if (v >= VOCAB) return;
    float s = 0.0f;
#pragma unroll
    for (int j = 0; j < NFT; ++j) s += partial[j * VOCAB + v];
    invn[v] = 1.0f / fmaxf(sqrtf(s), EPS);
}

// ---------------------------------------------------------------------------
// K2 (ILP-2, PLAIN stores): identical to R7 except the four
// __builtin_nontemporal_store are now plain f32x4 stores (single-variable A/B).
// ---------------------------------------------------------------------------
__global__ __launch_bounds__(256) void encode_bf16_ilp2(
        const int* __restrict__ ids, const unsigned short* __restrict__ Wt,
        const float* __restrict__ invn, float* __restrict__ out) {
    const int wv   = (int)((blockIdx.x * (unsigned long long)blockDim.x + threadIdx.x) >> 6);
    const int lane = threadIdx.x & 63;
    const int tok0 = wv * 2;
    if (tok0 >= NTOK) return;

    const int id0 = ids[tok0];
    const int id1 = ids[tok0 + 1];

    const uint4 r0 = *((const uint4*)(Wt + (size_t)id0 * FEAT) + lane);
    const uint4 r1 = *((const uint4*)(Wt + (size_t)id1 * FEAT) + lane);
    const float i0 = invn[id0];
    const float i1 = invn[id1];

    f32x4 a0 = {bflo(r0.x) * i0, bfhi(r0.x) * i0, bflo(r0.y) * i0, bfhi(r0.y) * i0};
    f32x4 a1 = {bflo(r0.z) * i0, bfhi(r0.z) * i0, bflo(r0.w) * i0, bfhi(r0.w) * i0};
    f32x4 c0 = {bflo(r1.x) * i1, bfhi(r1.x) * i1, bflo(r1.y) * i1, bfhi(r1.y) * i1};
    f32x4 c1 = {bflo(r1.z) * i1, bfhi(r1.z) * i1, bflo(r1.w) * i1, bfhi(r1.w) * i1};

    f32x4* d0 = (f32x4*)(out + (size_t)tok0 * FEAT + lane * 8);
    f32x4* d1 = (f32x4*)(out + (size_t)(tok0 + 1) * FEAT + lane * 8);
    d0[0] = a0;
    d0[1] = a1;
    d1[0] = c0;
    d1[1] = c1;
}

// ---------------------------------------------------------------------------
// Fallback (ws too small): direct strided gather from W with full reduction.
// ---------------------------------------------------------------------------
__global__ __launch_bounds__(256) void encode_direct(const int* __restrict__ ids,
                                                     const float* __restrict__ W,
                                                     const float* __restrict__ bias,
                                                     float* __restrict__ out) {
    const int tok  = (int)((blockIdx.x * (unsigned long long)blockDim.x + threadIdx.x) >> 6);
    const int lane = threadIdx.x & 63;
    if (tok >= NTOK) return;
    const int id = ids[tok];
    float x[8];
    float s = 0.0f;
#pragma unroll
    for (int j = 0; j < 8; ++j) {
        const int f = lane * 8 + j;
        x[j] = W[(size_t)f * VOCAB + id] + bias[f];
        s += x[j] * x[j];
    }
#pragma unroll
    for (int off = 32; off > 0; off >>= 1)
        s += __shfl_xor(s, off, 64);
    const float inv = 1.0f / fmaxf(sqrtf(s), EPS);
    float4 o0 = make_float4(x[0] * inv, x[1] * inv, x[2] * inv, x[3] * inv);
    float4 o1 = make_float4(x[4] * inv, x[5] * inv, x[6] * inv, x[7] * inv);
    float4* dst = (float4*)(out + (size_t)tok * FEAT + lane * 8);
    dst[0] = o0;
    dst[1] = o1;
}

extern "C" void kernel_launch(void* const* d_in, const int* in_sizes, int n_in,
                              void* d_out, int out_size, void* d_ws, size_t ws_size,
                              hipStream_t stream) {
    const int*   ids  = (const int*)d_in[0];
    const float* W    = (const float*)d_in[1];
    const float* bias = (const float*)d_in[2];
    float*       out  = (float*)d_out;

    const size_t wt_bytes   = (size_t)VOCAB * FEAT * sizeof(unsigned short); // 51.46 MB
    const size_t part_bytes = (size_t)NFT * VOCAB * sizeof(float);           // 1.6 MB
    const size_t inv_bytes  = (size_t)VOCAB * sizeof(float);                 // 0.2 MB

    if (ws_size >= wt_bytes + part_bytes + inv_bytes) {
        unsigned short* Wt = (unsigned short*)d_ws;
        float* partial     = (float*)((char*)d_ws + wt_bytes);
        float* invn        = (float*)((char*)d_ws + wt_bytes + part_bytes);
        dim3 tgrid((VOCAB + 63) / 64, FEAT / 64);       // (786, 8)
        transpose_bias_bf16<<<tgrid, 256, 0, stream>>>(W, bias, Wt, partial);
        norm_table<<<(VOCAB + 255) / 256, 256, 0, stream>>>(partial, invn);
        // NTOK/2 waves, 4 waves per 256-thr block
        encode_bf16_ilp2<<<NTOK / 8, 256, 0, stream>>>(ids, Wt, invn, out);
    } else {
        encode_direct<<<NTOK / 4, 256, 0, stream>>>(ids, W, bias, out);
    }
}